// Round 5
// baseline (336.037 us; speedup 1.0000x reference)
//
#include <hip/hip_runtime.h>
#include <math.h>

#define B_   24
#define NA_  50
#define T_   10
#define NV_  196
#define D_   512
#define M_   1200          // B*NA audio rows
#define MPAD 1280          // padded to 10 tiles of 128
#define NVP  224           // 196 padded to 14*16
#define YT_  240           // B*T
#define VROWS (YT_ * NVP)  // 53760 padded visual rows
#define ABLK 320           // MPAD/4 blocks handle audio in fused normconv

typedef __bf16 bf16x8 __attribute__((ext_vector_type(8)));
typedef float  f32x4  __attribute__((ext_vector_type(4)));
typedef unsigned short ushort8 __attribute__((ext_vector_type(8)));

__device__ __forceinline__ unsigned short f2bf(float f) {
    unsigned u = __float_as_uint(f);
    u += 0x7FFF + ((u >> 16) & 1);       // RNE
    return (unsigned short)(u >> 16);
}

__device__ __forceinline__ void gload16(const void* g, void* l) {
    __builtin_amdgcn_global_load_lds(
        (const __attribute__((address_space(1))) unsigned int*)g,
        (__attribute__((address_space(3))) unsigned int*)l, 16, 0, 0);
}

// ---- fused L2-normalize + bf16 convert for BOTH inputs, + accs/counter zeroing ----
// blocks [0, ABLK): audio rows (scaled by 1/temperature); [ABLK, ...): visual rows.
__global__ void normconv_kernel(const float* __restrict__ a,
                                const float* __restrict__ vf,
                                const float* __restrict__ tempPtr,
                                unsigned short* __restrict__ Abf,
                                unsigned short* __restrict__ Vbf,
                                float* __restrict__ accs) {
    if (blockIdx.x == 0 && threadIdx.x < 4) accs[threadIdx.x] = 0.0f; // [nonneg,frac,sel,counter]
    int w = threadIdx.x >> 6, lane = threadIdx.x & 63;
    int bid = blockIdx.x;
    const float* src = nullptr;
    ushort8* dst;
    float tscale = 1.0f;
    if (bid < ABLK) {
        int row = bid * 4 + w;                 // < MPAD
        dst = (ushort8*)(Abf + (size_t)row * D_ + lane * 8);
        if (row < M_) { src = a + (size_t)row * D_ + lane * 8; tscale = tempPtr[0]; }
    } else {
        int row = (bid - ABLK) * 4 + w;        // < VROWS
        dst = (ushort8*)(Vbf + (size_t)row * D_ + lane * 8);
        int yt = row / NVP, vv = row - yt * NVP;
        if (vv < NV_) src = vf + ((size_t)yt * NV_ + vv) * D_ + lane * 8;
    }
    if (src) {
        float4 u = *(const float4*)src;
        float4 v = *(const float4*)(src + 4);
        float s = u.x*u.x + u.y*u.y + u.z*u.z + u.w*u.w
                + v.x*v.x + v.y*v.y + v.z*v.z + v.w*v.w;
        #pragma unroll
        for (int off = 32; off; off >>= 1) s += __shfl_xor(s, off, 64);
        float sc = 1.0f / (fmaxf(sqrtf(s), 1e-12f) * tscale);
        ushort8 o;
        o[0]=f2bf(u.x*sc); o[1]=f2bf(u.y*sc); o[2]=f2bf(u.z*sc); o[3]=f2bf(u.w*sc);
        o[4]=f2bf(v.x*sc); o[5]=f2bf(v.y*sc); o[6]=f2bf(v.z*sc); o[7]=f2bf(v.w*sc);
        *dst = o;
    } else {
        ushort8 z = (ushort8)0;
        *dst = z;
    }
}

// ---- MFMA GEMM + fused max/clip reductions ----
// Double-buffered LDS with 1-chunk-ahead prefetch (minimum 2-phase), single
// barrier per chunk. XCD-aware bijective block swizzle keeps each XCD's
// V-panel working set L2-resident (R3-verified: FETCH 229->32 MB).
// 16B-chunk XOR swizzle on both sides kills the 8-way bank conflict
// (R1-verified: conflicts 6.76M -> 0).
#define BUFB 22528u   // bytes per K-chunk buffer: A 128*64 + V 224*64

__global__ __launch_bounds__(256) void simred_kernel(
    const unsigned short* __restrict__ Abf, const unsigned short* __restrict__ Vbf,
    float* __restrict__ maxvis, float* __restrict__ accNonneg)
{
    __shared__ __align__(16) unsigned char lds[2 * BUFB]; // [buf][A 8192 | V 14336]
    __shared__ float maxred[2][128];
    __shared__ float redbuf[4];

    const int tid  = threadIdx.x;
    const int lane = tid & 63;
    const int w    = tid >> 6;
    const int lrow = lane >> 2;    // staging: row within 16-row unit
    const int lcol = lane & 3;     // staging: 16B piece within 64B row
    const int q    = lane >> 4;    // frag quad
    const int m16  = lane & 15;
    const int wr   = w & 1;        // wave row half (64 rows)
    const int wc   = w >> 1;       // wave col half (112 cols)

    // XCD-aware bijective remap: 2400 blocks, 8 XCDs, 300 blocks/XCD.
    const int lin = blockIdx.y * gridDim.x + blockIdx.x;
    const int swz = (lin & 7) * 300 + (lin >> 3);
    const int bx  = swz % 10;
    const int yt  = swz / 10;
    const int rowA0 = bx * 128;
    const size_t vRow0 = (size_t)yt * NVP;

    // staging: pre-swizzle the per-lane global source column; LDS dest linear.
    const int scol = lcol ^ ((lrow >> 1) & 3);
    const unsigned short* gp[6];
    unsigned loff[6];
    int nun = 0;
    for (int u = w; u < 22; u += 4) {
        if (u < 8) gp[nun] = Abf + ((size_t)(rowA0 + u * 16 + lrow)) * D_ + scol * 8;
        else       gp[nun] = Vbf + (vRow0 + (size_t)((u - 8) * 16 + lrow)) * D_ + scol * 8;
        loff[nun] = (unsigned)u * 1024u;
        ++nun;
    }

    // fragment read offsets (A[m][k]: m=lane&15, k=q*8+j ; B same), swizzled.
    const unsigned rsw = (unsigned)((m16 >> 1) & 3) * 16u;  // per-lane constant key
    unsigned aoff[4], boff[7];
    #pragma unroll
    for (int i = 0; i < 4; ++i)
        aoff[i] = (unsigned)(wr * 64 + i * 16 + m16) * 64u + (((unsigned)q * 16u) ^ rsw);
    #pragma unroll
    for (int j = 0; j < 7; ++j)
        boff[j] = 8192u + (unsigned)(wc * 112 + j * 16 + m16) * 64u + (((unsigned)q * 16u) ^ rsw);

    f32x4 acc[4][7];
    #pragma unroll
    for (int i = 0; i < 4; ++i)
        #pragma unroll
        for (int j = 0; j < 7; ++j) acc[i][j] = (f32x4)0.0f;

    // prologue: stage chunk 0 into buf 0
    #pragma unroll 6
    for (int i = 0; i < 6; ++i)
        if (i < nun) gload16(gp[i], (void*)(lds + loff[i]));
    __syncthreads();   // implicit vmcnt(0): chunk 0 resident

    for (int c = 0; c < 16; ++c) {
        const unsigned char* buf = lds + (unsigned)(c & 1) * BUFB;
        // issue next chunk's loads FIRST — they fly during ds_read + MFMA below
        if (c < 15) {
            const int kc2 = (c + 1) * 32;
            const unsigned nb = (unsigned)((c + 1) & 1) * BUFB;
            #pragma unroll 6
            for (int i = 0; i < 6; ++i)
                if (i < nun) gload16(gp[i] + kc2, (void*)(lds + nb + loff[i]));
        }
        bf16x8 af[4], bfr[7];
        #pragma unroll
        for (int i = 0; i < 4; ++i) af[i] = *(const bf16x8*)(buf + aoff[i]);
        #pragma unroll
        for (int j = 0; j < 7; ++j) bfr[j] = *(const bf16x8*)(buf + boff[j]);
        #pragma unroll
        for (int i = 0; i < 4; ++i)
            #pragma unroll
            for (int j = 0; j < 7; ++j)
                acc[i][j] = __builtin_amdgcn_mfma_f32_16x16x32_bf16(af[i], bfr[j], acc[i][j], 0, 0, 0);
        __syncthreads();   // single drain point: vmcnt(0) prefetch + lgkm reads
    }

    // ---- clip(s,-20,0)^2 partial sum (zero-padded rows/cols contribute exactly 0) ----
    float cs = 0.0f;
    #pragma unroll
    for (int i = 0; i < 4; ++i)
        #pragma unroll
        for (int j = 0; j < 7; ++j)
            #pragma unroll
            for (int r = 0; r < 4; ++r) {
                float v = acc[i][j][r];
                float cv = fminf(fmaxf(v, -20.0f), 0.0f);
                cs += cv * cv;
            }
    #pragma unroll
    for (int off = 32; off; off >>= 1) cs += __shfl_xor(cs, off, 64);
    if (lane == 0) redbuf[w] = cs;

    // ---- per-row max over valid cols (C/D layout: col=lane&15, row=q*4+reg) ----
    bool colv[7];
    #pragma unroll
    for (int j = 0; j < 7; ++j) colv[j] = (wc * 112 + j * 16 + m16) < NV_;
    #pragma unroll
    for (int i = 0; i < 4; ++i) {
        float mx[4] = {-3e38f, -3e38f, -3e38f, -3e38f};
        #pragma unroll
        for (int j = 0; j < 7; ++j)
            #pragma unroll
            for (int r = 0; r < 4; ++r)
                mx[r] = fmaxf(mx[r], colv[j] ? acc[i][j][r] : -3e38f);
        #pragma unroll
        for (int r = 0; r < 4; ++r) {
            float mm = mx[r];
            #pragma unroll
            for (int off = 1; off <= 8; off <<= 1) mm = fmaxf(mm, __shfl_xor(mm, off, 64));
            if (m16 == 0) maxred[wc][wr * 64 + i * 16 + q * 4 + r] = mm;
        }
    }
    __syncthreads();
    if (tid == 0) atomicAdd(accNonneg, redbuf[0] + redbuf[1] + redbuf[2] + redbuf[3]);
    if (tid < 128) {
        float mm = fmaxf(maxred[0][tid], maxred[1][tid]);
        int R = rowA0 + tid;
        if (R < M_) {
            int x = R / NA_, a = R - x * NA_;
            int y = yt / T_, t = yt - y * T_;
            maxvis[(((size_t)x * B_ + y) * NA_ + a) * T_ + t] = mm;
        }
    }
}

// ---------------- aggregation + last-block finalize ----------------
// 576 blocks x 64 threads. Each block handles one (x,y); the LAST block to
// finish runs the finalize with its 64 threads. Device-scope counter in
// accs[3]; release fence before the counter RMW, acquire fence after.
// Trigger uses (count % 576)==575 so it fires exactly once per 576 arrivals
// even if a profiler replays this dispatch without re-running normconv.
__global__ void aggfin_kernel(const float* __restrict__ maxvis,
                              const float* __restrict__ thrPtr,
                              const float* __restrict__ scalePtr,
                              const float* __restrict__ tempPtr,
                              float* __restrict__ clipSims,
                              float* __restrict__ accs,
                              float* __restrict__ out)
{
    int xy = blockIdx.x;
    int x = xy / B_, y = xy % B_;
    int a = threadIdx.x;
    float th    = 1.0f / (1.0f + expf(-thrPtr[0]));
    float scale = scalePtr[0];
    float token = 0.0f, cnt = 0.0f, selsum = 0.0f;
    if (a < NA_) {
        const float* p = maxvis + (((size_t)x * B_ + y) * NA_ + a) * T_;
        float ws = 0.0f, ss = 0.0f;
        #pragma unroll
        for (int t = 0; t < T_; ++t) {
            float mv  = p[t];
            float rd  = mv - th;
            float sel = fmaxf(rd, 0.0f) * scale;
            ws += mv * sel;
            ss += sel;
            if (rd > 0.0f) cnt += 1.0f;
            if (x == y) selsum += 0.5f * (tanhf(20.0f * rd) + 1.0f);
        }
        token = ws / fmaxf(ss, 1e-6f);
    }
    #pragma unroll
    for (int off = 32; off; off >>= 1) {
        token  += __shfl_xor(token,  off, 64);
        cnt    += __shfl_xor(cnt,    off, 64);
        selsum += __shfl_xor(selsum, off, 64);
    }
    if (threadIdx.x == 0) {
        clipSims[x * B_ + y] = token / (float)NA_;
        atomicAdd(&accs[1], cnt);
        if (x == y) atomicAdd(&accs[2], selsum);
    }
    __threadfence();                      // release: our writes visible device-wide
    unsigned last = 0;
    if (threadIdx.x == 0) {
        unsigned v = atomicAdd((unsigned int*)(accs + 3), 1u);
        last = ((v % (unsigned)(B_ * B_)) == (unsigned)(B_ * B_ - 1));
    }
    last = __shfl((int)last, 0, 64);
    if (!last) return;
    __threadfence();                      // acquire: see all other blocks' writes

    // ---- finalize (64 threads of the last block) ----
    __shared__ float cs[B_ * B_];
    int tid = threadIdx.x;
    for (int i = tid; i < B_ * B_; i += 64) cs[i] = clipSims[i];
    __syncthreads();
    float lsum = 0.0f;
    if (tid < B_) {
        int i = tid;
        float m = -1e30f;
        for (int j = 0; j < B_; ++j) m = fmaxf(m, cs[i * B_ + j]);
        float e = 0.0f;
        for (int j = 0; j < B_; ++j) e += expf(cs[i * B_ + j] - m);
        float la = m + logf(e) - cs[i * B_ + i];
        float m2 = -1e30f;
        for (int j = 0; j < B_; ++j) m2 = fmaxf(m2, cs[j * B_ + i]);
        float e2 = 0.0f;
        for (int j = 0; j < B_; ++j) e2 += expf(cs[j * B_ + i] - m2);
        float lv = m2 + logf(e2) - cs[i * B_ + i];
        lsum = la + lv;
    }
    #pragma unroll
    for (int off = 32; off; off >>= 1) lsum += __shfl_xor(lsum, off, 64);
    if (tid == 0) {
        float contrastive = lsum / (float)B_ * 0.5f;
        float temp = tempPtr[0], scl = scalePtr[0];
        float l_nonneg = accs[0] / 56448000.0f;   // B*B*NA*T*NV
        float logt = logf(temp);
        float tl  = fmaxf(-logt, 0.0f);
        float thi = fmaxf(logt - logf(4.0f), 0.0f);
        float l_cal = tl * tl + thi * thi;
        float t1 = fmaxf(th - 0.9f, 0.0f), t2 = fmaxf(0.1f - th, 0.0f);
        float l_thr = t1 * t1 + t2 * t2;
        float s1 = fmaxf(scl - 20.0f, 0.0f), s2 = fmaxf(1.0f - scl, 0.0f);
        float l_scale = s1 * s1 + s2 * s2;
        float reg = 0.15f * l_nonneg + 2.0f * l_cal + 0.1f * l_thr + 0.1f * l_scale;
        float frac   = accs[1] / 288000.0f;       // B*B*NA*T
        float selrew = -0.1f * log1pf(accs[2] / 12000.0f); // B*NA*T
        out[0] = selrew + contrastive + reg;
        out[1] = contrastive;
        out[2] = reg;
        out[3] = frac;
        out[4] = selrew;
    }
}

extern "C" void kernel_launch(void* const* d_in, const int* in_sizes, int n_in,
                              void* d_out, int out_size, void* d_ws, size_t ws_size,
                              hipStream_t stream) {
    const float* audio  = (const float*)d_in[0];  // (24,50,512)
    const float* visual = (const float*)d_in[1];  // (24,10,196,512)
    const float* temp   = (const float*)d_in[2];
    const float* scale  = (const float*)d_in[3];
    const float* thr    = (const float*)d_in[4];
    float* out = (float*)d_out;

    unsigned char* wsb = (unsigned char*)d_ws;
    unsigned short* Abf = (unsigned short*)wsb;                       // 1280*512*2    = 1,310,720 B
    unsigned short* Vbf = (unsigned short*)(wsb + 1310720);           // 53760*512*2   = 55,050,240 B
    float* maxvis   = (float*)(wsb + 1310720 + 55050240);             // 288000 floats = 1,152,000 B
    float* clipSims = (float*)(wsb + 1310720 + 55050240 + 1152000);   // 576 floats
    float* accs     = clipSims + 576;                                 // 4: [nonneg, frac, sel, counter]

    normconv_kernel<<<ABLK + VROWS / 4, 256, 0, stream>>>(audio, visual, temp, Abf, Vbf, accs);

    dim3 grid(MPAD / 128, YT_);
    simred_kernel<<<grid, 256, 0, stream>>>(Abf, Vbf, maxvis, accs);

    aggfin_kernel<<<B_ * B_, 64, 0, stream>>>(maxvis, thr, scale, temp, clipSims, accs, out);
}

// Round 6
// 295.731 us; speedup vs baseline: 1.1363x; 1.1363x over previous
//
#include <hip/hip_runtime.h>
#include <math.h>

#define B_   24
#define NA_  50
#define T_   10
#define NV_  196
#define D_   512
#define M_   1200          // B*NA audio rows
#define MPAD 1280          // padded to 5 tiles of 256
#define NVP  224           // 196 padded to 14*16
#define YT_  240           // B*T
#define VROWS (YT_ * NVP)  // 53760 padded visual rows
#define ABLK 320           // MPAD/4 blocks handle audio in fused normconv

typedef __bf16 bf16x8 __attribute__((ext_vector_type(8)));
typedef float  f32x4  __attribute__((ext_vector_type(4)));
typedef unsigned short ushort8 __attribute__((ext_vector_type(8)));

__device__ __forceinline__ unsigned short f2bf(float f) {
    unsigned u = __float_as_uint(f);
    u += 0x7FFF + ((u >> 16) & 1);       // RNE
    return (unsigned short)(u >> 16);
}

__device__ __forceinline__ void gload16(const void* g, void* l) {
    __builtin_amdgcn_global_load_lds(
        (const __attribute__((address_space(1))) unsigned int*)g,
        (__attribute__((address_space(3))) unsigned int*)l, 16, 0, 0);
}

// ---- fused L2-normalize + bf16 convert for BOTH inputs, + accs/counter zeroing ----
// blocks [0, ABLK): audio rows (scaled by 1/temperature); [ABLK, ...): visual rows.
__global__ void normconv_kernel(const float* __restrict__ a,
                                const float* __restrict__ vf,
                                const float* __restrict__ tempPtr,
                                unsigned short* __restrict__ Abf,
                                unsigned short* __restrict__ Vbf,
                                float* __restrict__ accs) {
    if (blockIdx.x == 0 && threadIdx.x < 4) accs[threadIdx.x] = 0.0f; // [nonneg,frac,sel,counter]
    int w = threadIdx.x >> 6, lane = threadIdx.x & 63;
    int bid = blockIdx.x;
    const float* src = nullptr;
    ushort8* dst;
    float tscale = 1.0f;
    if (bid < ABLK) {
        int row = bid * 4 + w;                 // < MPAD
        dst = (ushort8*)(Abf + (size_t)row * D_ + lane * 8);
        if (row < M_) { src = a + (size_t)row * D_ + lane * 8; tscale = tempPtr[0]; }
    } else {
        int row = (bid - ABLK) * 4 + w;        // < VROWS
        dst = (ushort8*)(Vbf + (size_t)row * D_ + lane * 8);
        int yt = row / NVP, vv = row - yt * NVP;
        if (vv < NV_) src = vf + ((size_t)yt * NV_ + vv) * D_ + lane * 8;
    }
    if (src) {
        float4 u = *(const float4*)src;
        float4 v = *(const float4*)(src + 4);
        float s = u.x*u.x + u.y*u.y + u.z*u.z + u.w*u.w
                + v.x*v.x + v.y*v.y + v.z*v.z + v.w*v.w;
        #pragma unroll
        for (int off = 32; off; off >>= 1) s += __shfl_xor(s, off, 64);
        float sc = 1.0f / (fmaxf(sqrtf(s), 1e-12f) * tscale);
        ushort8 o;
        o[0]=f2bf(u.x*sc); o[1]=f2bf(u.y*sc); o[2]=f2bf(u.z*sc); o[3]=f2bf(u.w*sc);
        o[4]=f2bf(v.x*sc); o[5]=f2bf(v.y*sc); o[6]=f2bf(v.z*sc); o[7]=f2bf(v.w*sc);
        *dst = o;
    } else {
        ushort8 z = (ushort8)0;
        *dst = z;
    }
}

// ---- MFMA GEMM + fused max/clip reductions ----
// STAGING-BANDWIDTH-BOUND regime (R5 evidence): 864 MB/dispatch streamed
// through L2/L3 at ~8 TB/s was the R3 floor. Fix = arithmetic intensity:
// 256x224 tile (8 waves) stages A 262K + V 229K = 491 KB per 2x output,
// total 590 MB (-32%). Keep R3's verified single-buffer 2-barrier schedule,
// XCD-aware bijective swizzle (FETCH 229->32 MB, R3) and both-sides LDS
// XOR swizzle (conflicts 6.76M->0, R1).
__global__ __launch_bounds__(512) void simred_kernel(
    const unsigned short* __restrict__ Abf, const unsigned short* __restrict__ Vbf,
    float* __restrict__ maxvis, float* __restrict__ accNonneg)
{
    __shared__ __align__(16) unsigned char lds[16384 + 14336]; // As[256][32bf16] | Vs[224][32bf16]
    __shared__ float maxred[2][256];
    __shared__ float redbuf[8];

    const int tid  = threadIdx.x;
    const int lane = tid & 63;
    const int w    = tid >> 6;     // 8 waves
    const int lrow = lane >> 2;    // staging: row within 16-row unit
    const int lcol = lane & 3;     // staging: 16B piece within 64B row
    const int q    = lane >> 4;    // frag quad
    const int m16  = lane & 15;
    const int wr   = w & 3;        // wave row quarter (64 rows each)
    const int wc   = w >> 2;       // wave col half (112 cols each)

    // XCD-aware bijective remap: 1200 blocks, 8 XCDs, 150 blocks/XCD.
    // XCD x owns swz in [150x,150x+150) -> yt in [30x,30x+30) (same
    // partition R3 verified L2-resident).
    const int lin = blockIdx.y * gridDim.x + blockIdx.x;
    const int swz = (lin & 7) * 150 + (lin >> 3);
    const int bx  = swz % 5;
    const int yt  = swz / 5;
    const int rowA0 = bx * 256;
    const size_t vRow0 = (size_t)yt * NVP;

    // staging: pre-swizzle the per-lane global source column; LDS dest linear.
    // units: 0..15 = A rows u*16.., 16..29 = V rows (u-16)*16..
    const int scol = lcol ^ ((lrow >> 1) & 3);
    const unsigned short* gp[4];
    const unsigned char*  lp[4];
    int nun = 0;
    for (int u = w; u < 30; u += 8) {
        if (u < 16) gp[nun] = Abf + ((size_t)(rowA0 + u * 16 + lrow)) * D_ + scol * 8;
        else        gp[nun] = Vbf + (vRow0 + (size_t)((u - 16) * 16 + lrow)) * D_ + scol * 8;
        lp[nun] = lds + u * 1024;
        ++nun;
    }

    // fragment read offsets (A[m][k]: m=lane&15, k=q*8+j ; B same), swizzled.
    const unsigned rsw = (unsigned)((m16 >> 1) & 3) * 16u;  // per-lane constant key
    unsigned aoff[4], boff[7];
    #pragma unroll
    for (int i = 0; i < 4; ++i)
        aoff[i] = (unsigned)(wr * 64 + i * 16 + m16) * 64u + (((unsigned)q * 16u) ^ rsw);
    #pragma unroll
    for (int j = 0; j < 7; ++j)
        boff[j] = 16384u + (unsigned)(wc * 112 + j * 16 + m16) * 64u + (((unsigned)q * 16u) ^ rsw);

    f32x4 acc[4][7];
    #pragma unroll
    for (int i = 0; i < 4; ++i)
        #pragma unroll
        for (int j = 0; j < 7; ++j) acc[i][j] = (f32x4)0.0f;

    for (int c = 0; c < 16; ++c) {
        const int kc = c * 32;
        __syncthreads();                       // prev chunk's frag reads done
        #pragma unroll 4
        for (int i = 0; i < 4; ++i)
            if (i < nun) gload16(gp[i] + kc, (void*)lp[i]);
        __syncthreads();                       // staging complete (vmcnt drained)
        bf16x8 af[4], bfr[7];
        #pragma unroll
        for (int i = 0; i < 4; ++i) af[i] = *(const bf16x8*)(lds + aoff[i]);
        #pragma unroll
        for (int j = 0; j < 7; ++j) bfr[j] = *(const bf16x8*)(lds + boff[j]);
        #pragma unroll
        for (int i = 0; i < 4; ++i)
            #pragma unroll
            for (int j = 0; j < 7; ++j)
                acc[i][j] = __builtin_amdgcn_mfma_f32_16x16x32_bf16(af[i], bfr[j], acc[i][j], 0, 0, 0);
    }

    // ---- clip(s,-20,0)^2 partial sum (zero-padded rows/cols contribute exactly 0) ----
    float cs = 0.0f;
    #pragma unroll
    for (int i = 0; i < 4; ++i)
        #pragma unroll
        for (int j = 0; j < 7; ++j)
            #pragma unroll
            for (int r = 0; r < 4; ++r) {
                float v = acc[i][j][r];
                float cv = fminf(fmaxf(v, -20.0f), 0.0f);
                cs += cv * cv;
            }
    #pragma unroll
    for (int off = 32; off; off >>= 1) cs += __shfl_xor(cs, off, 64);
    if (lane == 0) redbuf[w] = cs;

    // ---- per-row max over valid cols (C/D layout: col=lane&15, row=q*4+reg) ----
    bool colv[7];
    #pragma unroll
    for (int j = 0; j < 7; ++j) colv[j] = (wc * 112 + j * 16 + m16) < NV_;
    #pragma unroll
    for (int i = 0; i < 4; ++i) {
        float mx[4] = {-3e38f, -3e38f, -3e38f, -3e38f};
        #pragma unroll
        for (int j = 0; j < 7; ++j)
            #pragma unroll
            for (int r = 0; r < 4; ++r)
                mx[r] = fmaxf(mx[r], colv[j] ? acc[i][j][r] : -3e38f);
        #pragma unroll
        for (int r = 0; r < 4; ++r) {
            float mm = mx[r];
            #pragma unroll
            for (int off = 1; off <= 8; off <<= 1) mm = fmaxf(mm, __shfl_xor(mm, off, 64));
            if (m16 == 0) maxred[wc][wr * 64 + i * 16 + q * 4 + r] = mm;
        }
    }
    __syncthreads();
    if (tid == 0) atomicAdd(accNonneg, redbuf[0] + redbuf[1] + redbuf[2] + redbuf[3]
                                     + redbuf[4] + redbuf[5] + redbuf[6] + redbuf[7]);
    if (tid < 256) {
        float mm = fmaxf(maxred[0][tid], maxred[1][tid]);
        int R = rowA0 + tid;
        if (R < M_) {
            int x = R / NA_, a = R - x * NA_;
            int y = yt / T_, t = yt - y * T_;
            maxvis[(((size_t)x * B_ + y) * NA_ + a) * T_ + t] = mm;
        }
    }
}

// ---------------- aggregation + last-block finalize ----------------
// 576 blocks x 64 threads. Each block handles one (x,y); the LAST block to
// finish runs the finalize with its 64 threads. Device-scope counter in
// accs[3]; release fence before the counter RMW, acquire fence after.
// Trigger uses (count % 576)==575 so it fires exactly once per 576 arrivals
// even if a profiler replays this dispatch without re-running normconv.
__global__ void aggfin_kernel(const float* __restrict__ maxvis,
                              const float* __restrict__ thrPtr,
                              const float* __restrict__ scalePtr,
                              const float* __restrict__ tempPtr,
                              float* __restrict__ clipSims,
                              float* __restrict__ accs,
                              float* __restrict__ out)
{
    int xy = blockIdx.x;
    int x = xy / B_, y = xy % B_;
    int a = threadIdx.x;
    float th    = 1.0f / (1.0f + expf(-thrPtr[0]));
    float scale = scalePtr[0];
    float token = 0.0f, cnt = 0.0f, selsum = 0.0f;
    if (a < NA_) {
        const float* p = maxvis + (((size_t)x * B_ + y) * NA_ + a) * T_;
        float ws = 0.0f, ss = 0.0f;
        #pragma unroll
        for (int t = 0; t < T_; ++t) {
            float mv  = p[t];
            float rd  = mv - th;
            float sel = fmaxf(rd, 0.0f) * scale;
            ws += mv * sel;
            ss += sel;
            if (rd > 0.0f) cnt += 1.0f;
            if (x == y) selsum += 0.5f * (tanhf(20.0f * rd) + 1.0f);
        }
        token = ws / fmaxf(ss, 1e-6f);
    }
    #pragma unroll
    for (int off = 32; off; off >>= 1) {
        token  += __shfl_xor(token,  off, 64);
        cnt    += __shfl_xor(cnt,    off, 64);
        selsum += __shfl_xor(selsum, off, 64);
    }
    if (threadIdx.x == 0) {
        clipSims[x * B_ + y] = token / (float)NA_;
        atomicAdd(&accs[1], cnt);
        if (x == y) atomicAdd(&accs[2], selsum);
    }
    __threadfence();                      // release: our writes visible device-wide
    unsigned last = 0;
    if (threadIdx.x == 0) {
        unsigned v = atomicAdd((unsigned int*)(accs + 3), 1u);
        last = ((v % (unsigned)(B_ * B_)) == (unsigned)(B_ * B_ - 1));
    }
    last = __shfl((int)last, 0, 64);
    if (!last) return;
    __threadfence();                      // acquire: see all other blocks' writes

    // ---- finalize (64 threads of the last block) ----
    __shared__ float cs[B_ * B_];
    int tid = threadIdx.x;
    for (int i = tid; i < B_ * B_; i += 64) cs[i] = clipSims[i];
    __syncthreads();
    float lsum = 0.0f;
    if (tid < B_) {
        int i = tid;
        float m = -1e30f;
        for (int j = 0; j < B_; ++j) m = fmaxf(m, cs[i * B_ + j]);
        float e = 0.0f;
        for (int j = 0; j < B_; ++j) e += expf(cs[i * B_ + j] - m);
        float la = m + logf(e) - cs[i * B_ + i];
        float m2 = -1e30f;
        for (int j = 0; j < B_; ++j) m2 = fmaxf(m2, cs[j * B_ + i]);
        float e2 = 0.0f;
        for (int j = 0; j < B_; ++j) e2 += expf(cs[j * B_ + i] - m2);
        float lv = m2 + logf(e2) - cs[i * B_ + i];
        lsum = la + lv;
    }
    #pragma unroll
    for (int off = 32; off; off >>= 1) lsum += __shfl_xor(lsum, off, 64);
    if (tid == 0) {
        float contrastive = lsum / (float)B_ * 0.5f;
        float temp = tempPtr[0], scl = scalePtr[0];
        float l_nonneg = accs[0] / 56448000.0f;   // B*B*NA*T*NV
        float logt = logf(temp);
        float tl  = fmaxf(-logt, 0.0f);
        float thi = fmaxf(logt - logf(4.0f), 0.0f);
        float l_cal = tl * tl + thi * thi;
        float t1 = fmaxf(th - 0.9f, 0.0f), t2 = fmaxf(0.1f - th, 0.0f);
        float l_thr = t1 * t1 + t2 * t2;
        float s1 = fmaxf(scl - 20.0f, 0.0f), s2 = fmaxf(1.0f - scl, 0.0f);
        float l_scale = s1 * s1 + s2 * s2;
        float reg = 0.15f * l_nonneg + 2.0f * l_cal + 0.1f * l_thr + 0.1f * l_scale;
        float frac   = accs[1] / 288000.0f;       // B*B*NA*T
        float selrew = -0.1f * log1pf(accs[2] / 12000.0f); // B*NA*T
        out[0] = selrew + contrastive + reg;
        out[1] = contrastive;
        out[2] = reg;
        out[3] = frac;
        out[4] = selrew;
    }
}

extern "C" void kernel_launch(void* const* d_in, const int* in_sizes, int n_in,
                              void* d_out, int out_size, void* d_ws, size_t ws_size,
                              hipStream_t stream) {
    const float* audio  = (const float*)d_in[0];  // (24,50,512)
    const float* visual = (const float*)d_in[1];  // (24,10,196,512)
    const float* temp   = (const float*)d_in[2];
    const float* scale  = (const float*)d_in[3];
    const float* thr    = (const float*)d_in[4];
    float* out = (float*)d_out;

    unsigned char* wsb = (unsigned char*)d_ws;
    unsigned short* Abf = (unsigned short*)wsb;                       // 1280*512*2    = 1,310,720 B
    unsigned short* Vbf = (unsigned short*)(wsb + 1310720);           // 53760*512*2   = 55,050,240 B
    float* maxvis   = (float*)(wsb + 1310720 + 55050240);             // 288000 floats = 1,152,000 B
    float* clipSims = (float*)(wsb + 1310720 + 55050240 + 1152000);   // 576 floats
    float* accs     = clipSims + 576;                                 // 4: [nonneg, frac, sel, counter]

    normconv_kernel<<<ABLK + VROWS / 4, 256, 0, stream>>>(audio, visual, temp, Abf, Vbf, accs);

    dim3 grid(MPAD / 256, YT_);
    simred_kernel<<<grid, 512, 0, stream>>>(Abf, Vbf, maxvis, accs);

    aggfin_kernel<<<B_ * B_, 64, 0, stream>>>(maxvis, thr, scale, temp, clipSims, accs, out);
}

// Round 7
// 285.930 us; speedup vs baseline: 1.1752x; 1.0343x over previous
//
#include <hip/hip_runtime.h>
#include <math.h>

#define B_   24
#define NA_  50
#define T_   10
#define NV_  196
#define D_   512
#define M_   1200          // B*NA audio rows
#define MPAD 1280          // padded to 10 tiles of 128
#define NVP  224           // 196 padded to 14*16
#define YT_  240           // B*T
#define VROWS (YT_ * NVP)  // 53760 padded visual rows
#define ABLK 320           // MPAD/4 blocks handle audio in fused normconv

typedef __bf16 bf16x8 __attribute__((ext_vector_type(8)));
typedef float  f32x4  __attribute__((ext_vector_type(4)));
typedef unsigned short ushort8 __attribute__((ext_vector_type(8)));

__device__ __forceinline__ unsigned short f2bf(float f) {
    unsigned u = __float_as_uint(f);
    u += 0x7FFF + ((u >> 16) & 1);       // RNE
    return (unsigned short)(u >> 16);
}

__device__ __forceinline__ void gload16(const void* g, void* l) {
    __builtin_amdgcn_global_load_lds(
        (const __attribute__((address_space(1))) unsigned int*)g,
        (__attribute__((address_space(3))) unsigned int*)l, 16, 0, 0);
}

// ---- fused L2-normalize + bf16 convert for BOTH inputs, + accs/counter zeroing ----
// blocks [0, ABLK): audio rows (scaled by 1/temperature); [ABLK, ...): visual rows.
__global__ void normconv_kernel(const float* __restrict__ a,
                                const float* __restrict__ vf,
                                const float* __restrict__ tempPtr,
                                unsigned short* __restrict__ Abf,
                                unsigned short* __restrict__ Vbf,
                                float* __restrict__ accs) {
    if (blockIdx.x == 0 && threadIdx.x < 4) accs[threadIdx.x] = 0.0f; // [nonneg,frac,sel,counter]
    int w = threadIdx.x >> 6, lane = threadIdx.x & 63;
    int bid = blockIdx.x;
    const float* src = nullptr;
    ushort8* dst;
    float tscale = 1.0f;
    if (bid < ABLK) {
        int row = bid * 4 + w;                 // < MPAD
        dst = (ushort8*)(Abf + (size_t)row * D_ + lane * 8);
        if (row < M_) { src = a + (size_t)row * D_ + lane * 8; tscale = tempPtr[0]; }
    } else {
        int row = (bid - ABLK) * 4 + w;        // < VROWS
        dst = (ushort8*)(Vbf + (size_t)row * D_ + lane * 8);
        int yt = row / NVP, vv = row - yt * NVP;
        if (vv < NV_) src = vf + ((size_t)yt * NV_ + vv) * D_ + lane * 8;
    }
    if (src) {
        float4 u = *(const float4*)src;
        float4 v = *(const float4*)(src + 4);
        float s = u.x*u.x + u.y*u.y + u.z*u.z + u.w*u.w
                + v.x*v.x + v.y*v.y + v.z*v.z + v.w*v.w;
        #pragma unroll
        for (int off = 32; off; off >>= 1) s += __shfl_xor(s, off, 64);
        float sc = 1.0f / (fmaxf(sqrtf(s), 1e-12f) * tscale);
        ushort8 o;
        o[0]=f2bf(u.x*sc); o[1]=f2bf(u.y*sc); o[2]=f2bf(u.z*sc); o[3]=f2bf(u.w*sc);
        o[4]=f2bf(v.x*sc); o[5]=f2bf(v.y*sc); o[6]=f2bf(v.z*sc); o[7]=f2bf(v.w*sc);
        *dst = o;
    } else {
        ushort8 z = (ushort8)0;
        *dst = z;
    }
}

// ---- MFMA GEMM + fused max/clip reductions ----
// R3 geometry (128x224 tile, 4 waves, 24KB single-buffer LDS, 2400 blocks)
// with the chunk body REORDERED for intra-block overlap at zero LDS cost:
//   ds_read frags(c) -> barrier -> issue gload_lds(c+1) into the SAME
//   buffer -> MFMA(c) concurrent with the loads in flight -> barrier.
// The ~400cyc L2 staging latency hides under the ~540cyc MFMA phase
// (R6 falsified the staging-BW model: -32% bytes gave +12% time; the
// binding term is the serially-exposed per-chunk staging latency).
// XCD-aware bijective swizzle (R3: FETCH 229->32 MB) and both-sides LDS
// XOR swizzle (R1: conflicts 6.76M->0) retained.
__global__ __launch_bounds__(256) void simred_kernel(
    const unsigned short* __restrict__ Abf, const unsigned short* __restrict__ Vbf,
    float* __restrict__ maxvis, float* __restrict__ accNonneg)
{
    __shared__ __align__(16) unsigned char lds[8192 + 14336]; // As[128][32bf16] | Vs[224][32bf16]
    __shared__ float maxred[2][128];
    __shared__ float redbuf[4];

    const int tid  = threadIdx.x;
    const int lane = tid & 63;
    const int w    = tid >> 6;
    const int lrow = lane >> 2;    // staging: row within 16-row unit
    const int lcol = lane & 3;     // staging: 16B piece within 64B row
    const int q    = lane >> 4;    // frag quad
    const int m16  = lane & 15;
    const int wr   = w & 1;        // wave row half (64 rows)
    const int wc   = w >> 1;       // wave col half (112 cols)

    // XCD-aware bijective remap: 2400 blocks, 8 XCDs, 300 blocks/XCD.
    const int lin = blockIdx.y * gridDim.x + blockIdx.x;
    const int swz = (lin & 7) * 300 + (lin >> 3);
    const int bx  = swz % 10;
    const int yt  = swz / 10;
    const int rowA0 = bx * 128;
    const size_t vRow0 = (size_t)yt * NVP;

    // staging: pre-swizzle the per-lane global source column; LDS dest linear.
    const int scol = lcol ^ ((lrow >> 1) & 3);
    const unsigned short* gp[6];
    const unsigned char*  lp[6];
    int nun = 0;
    for (int u = w; u < 22; u += 4) {
        if (u < 8) gp[nun] = Abf + ((size_t)(rowA0 + u * 16 + lrow)) * D_ + scol * 8;
        else       gp[nun] = Vbf + (vRow0 + (size_t)((u - 8) * 16 + lrow)) * D_ + scol * 8;
        lp[nun] = lds + u * 1024;
        ++nun;
    }

    // fragment read offsets (A[m][k]: m=lane&15, k=q*8+j ; B same), swizzled.
    const unsigned rsw = (unsigned)((m16 >> 1) & 3) * 16u;  // per-lane constant key
    unsigned aoff[4], boff[7];
    #pragma unroll
    for (int i = 0; i < 4; ++i)
        aoff[i] = (unsigned)(wr * 64 + i * 16 + m16) * 64u + (((unsigned)q * 16u) ^ rsw);
    #pragma unroll
    for (int j = 0; j < 7; ++j)
        boff[j] = 8192u + (unsigned)(wc * 112 + j * 16 + m16) * 64u + (((unsigned)q * 16u) ^ rsw);

    f32x4 acc[4][7];
    #pragma unroll
    for (int i = 0; i < 4; ++i)
        #pragma unroll
        for (int j = 0; j < 7; ++j) acc[i][j] = (f32x4)0.0f;

    // prologue: stage chunk 0
    #pragma unroll 6
    for (int i = 0; i < 6; ++i)
        if (i < nun) gload16(gp[i], (void*)lp[i]);
    __syncthreads();   // implicit vmcnt(0): chunk 0 resident

    for (int c = 0; c < 16; ++c) {
        // 1. pull this chunk's fragments into registers
        bf16x8 af[4], bfr[7];
        #pragma unroll
        for (int i = 0; i < 4; ++i) af[i] = *(const bf16x8*)(lds + aoff[i]);
        #pragma unroll
        for (int j = 0; j < 7; ++j) bfr[j] = *(const bf16x8*)(lds + boff[j]);
        __syncthreads();   // all waves done reading the buffer (lgkm drained)
        // 2. immediately re-stage the buffer with the NEXT chunk
        if (c < 15) {
            const int kc2 = (c + 1) * 32;
            #pragma unroll 6
            for (int i = 0; i < 6; ++i)
                if (i < nun) gload16(gp[i] + kc2, (void*)lp[i]);
        }
        // 3. MFMA on registers — flies concurrently with the staging loads
        #pragma unroll
        for (int i = 0; i < 4; ++i)
            #pragma unroll
            for (int j = 0; j < 7; ++j)
                acc[i][j] = __builtin_amdgcn_mfma_f32_16x16x32_bf16(af[i], bfr[j], acc[i][j], 0, 0, 0);
        __syncthreads();   // vmcnt(0) drain: next chunk resident
    }

    // ---- clip(s,-20,0)^2 partial sum (zero-padded rows/cols contribute exactly 0) ----
    float cs = 0.0f;
    #pragma unroll
    for (int i = 0; i < 4; ++i)
        #pragma unroll
        for (int j = 0; j < 7; ++j)
            #pragma unroll
            for (int r = 0; r < 4; ++r) {
                float v = acc[i][j][r];
                float cv = fminf(fmaxf(v, -20.0f), 0.0f);
                cs += cv * cv;
            }
    #pragma unroll
    for (int off = 32; off; off >>= 1) cs += __shfl_xor(cs, off, 64);
    if (lane == 0) redbuf[w] = cs;

    // ---- per-row max over valid cols (C/D layout: col=lane&15, row=q*4+reg) ----
    bool colv[7];
    #pragma unroll
    for (int j = 0; j < 7; ++j) colv[j] = (wc * 112 + j * 16 + m16) < NV_;
    #pragma unroll
    for (int i = 0; i < 4; ++i) {
        float mx[4] = {-3e38f, -3e38f, -3e38f, -3e38f};
        #pragma unroll
        for (int j = 0; j < 7; ++j)
            #pragma unroll
            for (int r = 0; r < 4; ++r)
                mx[r] = fmaxf(mx[r], colv[j] ? acc[i][j][r] : -3e38f);
        #pragma unroll
        for (int r = 0; r < 4; ++r) {
            float mm = mx[r];
            #pragma unroll
            for (int off = 1; off <= 8; off <<= 1) mm = fmaxf(mm, __shfl_xor(mm, off, 64));
            if (m16 == 0) maxred[wc][wr * 64 + i * 16 + q * 4 + r] = mm;
        }
    }
    __syncthreads();
    if (tid == 0) atomicAdd(accNonneg, redbuf[0] + redbuf[1] + redbuf[2] + redbuf[3]);
    if (tid < 128) {
        float mm = fmaxf(maxred[0][tid], maxred[1][tid]);
        int R = rowA0 + tid;
        if (R < M_) {
            int x = R / NA_, a = R - x * NA_;
            int y = yt / T_, t = yt - y * T_;
            maxvis[(((size_t)x * B_ + y) * NA_ + a) * T_ + t] = mm;
        }
    }
}

// ---------------- aggregation + last-block finalize ----------------
// 576 blocks x 64 threads. Each block handles one (x,y); the LAST block to
// finish runs the finalize with its 64 threads. Device-scope counter in
// accs[3]; release fence before the counter RMW, acquire fence after.
// Trigger uses (count % 576)==575 so it fires exactly once per 576 arrivals
// even if a profiler replays this dispatch without re-running normconv.
__global__ void aggfin_kernel(const float* __restrict__ maxvis,
                              const float* __restrict__ thrPtr,
                              const float* __restrict__ scalePtr,
                              const float* __restrict__ tempPtr,
                              float* __restrict__ clipSims,
                              float* __restrict__ accs,
                              float* __restrict__ out)
{
    int xy = blockIdx.x;
    int x = xy / B_, y = xy % B_;
    int a = threadIdx.x;
    float th    = 1.0f / (1.0f + expf(-thrPtr[0]));
    float scale = scalePtr[0];
    float token = 0.0f, cnt = 0.0f, selsum = 0.0f;
    if (a < NA_) {
        const float* p = maxvis + (((size_t)x * B_ + y) * NA_ + a) * T_;
        float ws = 0.0f, ss = 0.0f;
        #pragma unroll
        for (int t = 0; t < T_; ++t) {
            float mv  = p[t];
            float rd  = mv - th;
            float sel = fmaxf(rd, 0.0f) * scale;
            ws += mv * sel;
            ss += sel;
            if (rd > 0.0f) cnt += 1.0f;
            if (x == y) selsum += 0.5f * (tanhf(20.0f * rd) + 1.0f);
        }
        token = ws / fmaxf(ss, 1e-6f);
    }
    #pragma unroll
    for (int off = 32; off; off >>= 1) {
        token  += __shfl_xor(token,  off, 64);
        cnt    += __shfl_xor(cnt,    off, 64);
        selsum += __shfl_xor(selsum, off, 64);
    }
    if (threadIdx.x == 0) {
        clipSims[x * B_ + y] = token / (float)NA_;
        atomicAdd(&accs[1], cnt);
        if (x == y) atomicAdd(&accs[2], selsum);
    }
    __threadfence();                      // release: our writes visible device-wide
    unsigned last = 0;
    if (threadIdx.x == 0) {
        unsigned v = atomicAdd((unsigned int*)(accs + 3), 1u);
        last = ((v % (unsigned)(B_ * B_)) == (unsigned)(B_ * B_ - 1));
    }
    last = __shfl((int)last, 0, 64);
    if (!last) return;
    __threadfence();                      // acquire: see all other blocks' writes

    // ---- finalize (64 threads of the last block) ----
    __shared__ float cs[B_ * B_];
    int tid = threadIdx.x;
    for (int i = tid; i < B_ * B_; i += 64) cs[i] = clipSims[i];
    __syncthreads();
    float lsum = 0.0f;
    if (tid < B_) {
        int i = tid;
        float m = -1e30f;
        for (int j = 0; j < B_; ++j) m = fmaxf(m, cs[i * B_ + j]);
        float e = 0.0f;
        for (int j = 0; j < B_; ++j) e += expf(cs[i * B_ + j] - m);
        float la = m + logf(e) - cs[i * B_ + i];
        float m2 = -1e30f;
        for (int j = 0; j < B_; ++j) m2 = fmaxf(m2, cs[j * B_ + i]);
        float e2 = 0.0f;
        for (int j = 0; j < B_; ++j) e2 += expf(cs[j * B_ + i] - m2);
        float lv = m2 + logf(e2) - cs[i * B_ + i];
        lsum = la + lv;
    }
    #pragma unroll
    for (int off = 32; off; off >>= 1) lsum += __shfl_xor(lsum, off, 64);
    if (tid == 0) {
        float contrastive = lsum / (float)B_ * 0.5f;
        float temp = tempPtr[0], scl = scalePtr[0];
        float l_nonneg = accs[0] / 56448000.0f;   // B*B*NA*T*NV
        float logt = logf(temp);
        float tl  = fmaxf(-logt, 0.0f);
        float thi = fmaxf(logt - logf(4.0f), 0.0f);
        float l_cal = tl * tl + thi * thi;
        float t1 = fmaxf(th - 0.9f, 0.0f), t2 = fmaxf(0.1f - th, 0.0f);
        float l_thr = t1 * t1 + t2 * t2;
        float s1 = fmaxf(scl - 20.0f, 0.0f), s2 = fmaxf(1.0f - scl, 0.0f);
        float l_scale = s1 * s1 + s2 * s2;
        float reg = 0.15f * l_nonneg + 2.0f * l_cal + 0.1f * l_thr + 0.1f * l_scale;
        float frac   = accs[1] / 288000.0f;       // B*B*NA*T
        float selrew = -0.1f * log1pf(accs[2] / 12000.0f); // B*NA*T
        out[0] = selrew + contrastive + reg;
        out[1] = contrastive;
        out[2] = reg;
        out[3] = frac;
        out[4] = selrew;
    }
}

extern "C" void kernel_launch(void* const* d_in, const int* in_sizes, int n_in,
                              void* d_out, int out_size, void* d_ws, size_t ws_size,
                              hipStream_t stream) {
    const float* audio  = (const float*)d_in[0];  // (24,50,512)
    const float* visual = (const float*)d_in[1];  // (24,10,196,512)
    const float* temp   = (const float*)d_in[2];
    const float* scale  = (const float*)d_in[3];
    const float* thr    = (const float*)d_in[4];
    float* out = (float*)d_out;

    unsigned char* wsb = (unsigned char*)d_ws;
    unsigned short* Abf = (unsigned short*)wsb;                       // 1280*512*2    = 1,310,720 B
    unsigned short* Vbf = (unsigned short*)(wsb + 1310720);           // 53760*512*2   = 55,050,240 B
    float* maxvis   = (float*)(wsb + 1310720 + 55050240);             // 288000 floats = 1,152,000 B
    float* clipSims = (float*)(wsb + 1310720 + 55050240 + 1152000);   // 576 floats
    float* accs     = clipSims + 576;                                 // 4: [nonneg, frac, sel, counter]

    normconv_kernel<<<ABLK + VROWS / 4, 256, 0, stream>>>(audio, visual, temp, Abf, Vbf, accs);

    dim3 grid(MPAD / 128, YT_);
    simred_kernel<<<grid, 256, 0, stream>>>(Abf, Vbf, maxvis, accs);

    aggfin_kernel<<<B_ * B_, 64, 0, stream>>>(maxvis, thr, scale, temp, clipSims, accs, out);
}